// Round 3
// baseline (108.134 us; speedup 1.0000x reference)
//
#include <hip/hip_runtime.h>
#include <hip/hip_bf16.h>
#include <stdint.h>

typedef short bf16x8 __attribute__((ext_vector_type(8)));
typedef float f32x4 __attribute__((ext_vector_type(4)));

#define DEVI static __device__ __forceinline__

constexpr int B_   = 32768;
constexpr int IN_  = 128;
constexpr int LF_  = 512;
constexpr int OUT_ = 32;

// ---- workspace layout (bytes) ----
// All B-side matrices stored in MFMA-fragment order:
//   chunk(tile,kstep) at base + chunk*64*16B; lane ln reads +ln*16B (coalesced).
// Fragment content for lane ln: row n = tile*16 + (ln&15), k = kstep*32 + (ln>>4)*8 .. +7.
constexpr size_t OFF_LTF = 0;                    // 32 tiles x 16 ks x 1KB = 524,288
constexpr size_t OFF_W1F = 524288;               // 32 tiles x 4 ks x 1KB  = 131,072
constexpr size_t OFF_W2F = OFF_W1F + 131072;     // 3 tiles x 16 ks x 1KB  = 49,152

DEVI short f2bs(float f) { __hip_bfloat16 h = __float2bfloat16(f); return *(short*)&h; }

// fast tanh: 1 - 2/(e^{2v}+1)
DEVI float tanh_fast(float v) {
    float e = __expf(2.0f * v);
    return 1.0f - 2.0f * __builtin_amdgcn_rcpf(e + 1.0f);
}

// coalesced fragment load: chunk = tile*ksteps + ks
DEVI bf16x8 fragGL(const __hip_bfloat16* base, int chunk, int ln) {
    return *(const bf16x8*)(base + ((size_t)chunk * 64 + ln) * 8);
}

// phi LDS tile: 64 rows x 64 chunks(16B); slot = row*64 + ((k>>3) ^ (row&7))
DEVI bf16x8 phiFrag(const char* p, int row, int kofs) {
    int c = (kofs >> 3) ^ (row & 7);
    return *(const bf16x8*)(p + (size_t)((row << 6) + c) * 16);
}
DEVI void phiStore(char* p, int row, int col, float v) {
    int c = (col >> 3) ^ (row & 7);
    *(short*)(p + (size_t)((row << 6) + c) * 16 + (col & 7) * 2) = f2bs(v);
}
// x LDS tile: 64 rows x 16 chunks; slot = row*16 + ((k>>3) ^ (row&15))
DEVI bf16x8 xFrag(const char* p, int row, int kofs) {
    int c = (kofs >> 3) ^ (row & 15);
    return *(const bf16x8*)(p + (size_t)((row << 4) + c) * 16);
}

// ---------------- prep: build fragment-order W1F / W2F / LTF ----------------
// one thread per 16B chunk: 8192 (w1f) + 3072 (w2f) + 32768 (ltf) = 44032
__global__ __launch_bounds__(256) void k_prep(
        const float* __restrict__ w1, const float* __restrict__ w2,
        const float* __restrict__ lv, const float* __restrict__ qb,
        __hip_bfloat16* __restrict__ w1f, __hip_bfloat16* __restrict__ w2f,
        __hip_bfloat16* __restrict__ ltf) {
    int cid = blockIdx.x * 256 + threadIdx.x;
    if (cid < 8192) {                       // W1F: nt(32) x ks(4) x ln(64)
        int ln = cid & 63, ks = (cid >> 6) & 3, nt = cid >> 8;
        int n = nt * 16 + (ln & 15), kb = ks * 32 + (ln >> 4) * 8;
        const float* src = w1 + (size_t)n * IN_ + kb;
        bf16x8 o;
#pragma unroll
        for (int i = 0; i < 8; ++i) o[i] = f2bs(src[i]);
        *(bf16x8*)(w1f + (size_t)cid * 8) = o;
    } else if (cid < 11264) {               // W2F: nt(3) x ks(16) x ln(64)
        int c2 = cid - 8192;
        int ln = c2 & 63, ks = (c2 >> 6) & 15, nt = c2 >> 10;
        int n = nt * 16 + (ln & 15), kb = ks * 32 + (ln >> 4) * 8;
        bf16x8 o;
#pragma unroll
        for (int i = 0; i < 8; ++i) {
            float v = (n < OUT_) ? w2[(size_t)n * LF_ + kb + i]
                                 : (n == OUT_ ? qb[kb + i] : 0.f);
            o[i] = f2bs(v);
        }
        *(bf16x8*)(w2f + (size_t)c2 * 8) = o;
    } else if (cid < 44032) {               // LTF: t(32) x ks(16) x ln(64)
        int c3 = cid - 11264;
        int ln = c3 & 63, ks = (c3 >> 6) & 15, t = c3 >> 10;
        int j = t * 16 + (ln & 15), kb = ks * 32 + (ln >> 4) * 8;
        bf16x8 o;
#pragma unroll
        for (int i = 0; i < 8; ++i) {
            int k = kb + i;                 // Lt[j][k] = L[k][j], zero for k<j
            o[i] = (k >= j) ? f2bs(lv[(size_t)k * (k + 1) / 2 + j]) : (short)0;
        }
        *(bf16x8*)(ltf + (size_t)c3 * 8) = o;
    }
}

// ---------------- fused: x->phi(LDS)->pi,vf ----------------
// M=64 rows/block, 512 blocks -> ALL resident (2 blocks/CU, one generation).
// LDS: phi 64KB | stage 16KB (x, then vfb/vfp alias) = 80KB.
// Register discipline: phase-1 loads B per-ni (live ~120 < 128 cap);
// phase-3 loads ltf fragments CONDITIONALLY (L2 traffic 139MB, not 524MB).
__global__ __launch_bounds__(512, 4) void k_fused(
        const float* __restrict__ x, const __hip_bfloat16* __restrict__ w1f,
        const float* __restrict__ b1, const __hip_bfloat16* __restrict__ w2f,
        const __hip_bfloat16* __restrict__ ltf, const float* __restrict__ qcp,
        float* __restrict__ pi, float* __restrict__ vf) {
    __shared__ char smem[81920];
    char*  phiB  = smem;
    char*  stage = smem + 65536;
    float* vfb   = (float*)stage;          // 64 f32 (alias; valid after phase-1 barrier)
    float* vfp   = (float*)(stage + 256);  // 8x64 f32

    const int tid = threadIdx.x, wv = tid >> 6, ln = tid & 63;
    const int cl = ln & 15, q = ln >> 4;
    const int m0 = blockIdx.x * 64;

    // ---- phase 0: load+cast x tile (64x128 fp32 -> bf16) into LDS ----
#pragma unroll
    for (int it = 0; it < 2; ++it) {
        int slot = it * 512 + tid, row = slot >> 4, cg = slot & 15;
        const float4* p = (const float4*)(x + (size_t)(m0 + row) * IN_ + cg * 8);
        float4 u0 = p[0], u1 = p[1];
        bf16x8 pk;
        pk[0] = f2bs(u0.x); pk[1] = f2bs(u0.y); pk[2] = f2bs(u0.z); pk[3] = f2bs(u0.w);
        pk[4] = f2bs(u1.x); pk[5] = f2bs(u1.y); pk[6] = f2bs(u1.z); pk[7] = f2bs(u1.w);
        *(bf16x8*)(stage + (size_t)((row << 4) + (cg ^ (row & 15))) * 16) = pk;
    }
    __syncthreads();

    // ---- phase 1: phi = tanh(x @ W1^T + b1); wave owns 64-col strip ----
    // B loaded per-ni (not preloaded x4) to keep live regs ~120 < 128 cap.
    {
        f32x4 acc[4][4] = {};   // 64 VGPRs
#pragma unroll
        for (int ks = 0; ks < 4; ++ks) {
            bf16x8 a[4];
#pragma unroll
            for (int mi = 0; mi < 4; ++mi) a[mi] = xFrag(stage, mi * 16 + cl, ks * 32 + q * 8);
#pragma unroll
            for (int ni = 0; ni < 4; ++ni) {
                bf16x8 b = fragGL(w1f, (4 * wv + ni) * 4 + ks, ln);
#pragma unroll
                for (int mi = 0; mi < 4; ++mi)
                    acc[mi][ni] = __builtin_amdgcn_mfma_f32_16x16x32_bf16(
                        a[mi], b, acc[mi][ni], 0, 0, 0);
            }
        }
#pragma unroll
        for (int ni = 0; ni < 4; ++ni) {
            int colg = wv * 64 + ni * 16 + cl;
            float bv = b1[colg];
#pragma unroll
            for (int mi = 0; mi < 4; ++mi)
#pragma unroll
                for (int r = 0; r < 4; ++r)
                    phiStore(phiB, mi * 16 + q * 4 + r, colg,
                             tanh_fast(acc[mi][ni][r] + bv));
        }
    }
    __syncthreads();   // phi complete; x/stage dead -> vfb/vfp alias valid

    // ---- phase 2: pi = phi @ W2ext^T; 12 (m,n) wave-tiles over 8 waves ----
    // waves 0-3 run two INTERLEAVED independent chains (halved dep latency).
    if (wv < 4) {
        int mi0 = (2 * wv) & 3, ni0 = (2 * wv) >> 2;
        int mi1 = (2 * wv + 1) & 3, ni1 = (2 * wv + 1) >> 2;
        f32x4 a20 = {}, a21 = {};
#pragma unroll 4
        for (int ks = 0; ks < 16; ++ks) {
            bf16x8 p0 = phiFrag(phiB, mi0 * 16 + cl, ks * 32 + q * 8);
            bf16x8 b0 = fragGL(w2f, ni0 * 16 + ks, ln);
            a20 = __builtin_amdgcn_mfma_f32_16x16x32_bf16(p0, b0, a20, 0, 0, 0);
            bf16x8 p1 = phiFrag(phiB, mi1 * 16 + cl, ks * 32 + q * 8);
            bf16x8 b1f = fragGL(w2f, ni1 * 16 + ks, ln);
            a21 = __builtin_amdgcn_mfma_f32_16x16x32_bf16(p1, b1f, a21, 0, 0, 0);
        }
#pragma unroll
        for (int r = 0; r < 4; ++r) {
            int row0 = mi0 * 16 + q * 4 + r, col0 = ni0 * 16 + cl;
            if (col0 < OUT_) pi[(size_t)(m0 + row0) * OUT_ + col0] = a20[r];
            int row1 = mi1 * 16 + q * 4 + r, col1 = ni1 * 16 + cl;
            if (col1 < OUT_) pi[(size_t)(m0 + row1) * OUT_ + col1] = a21[r];
        }
    } else {
        int mi = wv - 4, ni = 2;                    // tiles 8..11
        f32x4 a2a = {}, a2b = {};
#pragma unroll
        for (int ks = 0; ks < 16; ks += 2) {        // two chains over even/odd ks
            bf16x8 pe = phiFrag(phiB, mi * 16 + cl, ks * 32 + q * 8);
            bf16x8 be = fragGL(w2f, ni * 16 + ks, ln);
            a2a = __builtin_amdgcn_mfma_f32_16x16x32_bf16(pe, be, a2a, 0, 0, 0);
            bf16x8 po = phiFrag(phiB, mi * 16 + cl, (ks + 1) * 32 + q * 8);
            bf16x8 bo = fragGL(w2f, ni * 16 + ks + 1, ln);
            a2b = __builtin_amdgcn_mfma_f32_16x16x32_bf16(po, bo, a2b, 0, 0, 0);
        }
        f32x4 a2 = a2a + a2b;
#pragma unroll
        for (int r = 0; r < 4; ++r) {
            int row = mi * 16 + q * 4 + r, col = ni * 16 + cl;
            if (col < OUT_)       pi[(size_t)(m0 + row) * OUT_ + col] = a2[r];
            else if (col == OUT_) vfb[row] = a2[r];   // phi.qb
        }
    }

    // ---- phase 3: y = rowsum((phi @ L)^2); mirrored tiles, conditional loads ----
    {
        int tl[4] = { wv, 15 - wv, 16 + wv, 31 - wv };
        int kstart[4];
#pragma unroll
        for (int j = 0; j < 4; ++j) kstart[j] = (tl[j] * 16) & ~31;  // exact: Lt zero-padded
        int kmin = kstart[0];            // tl[0] is the smallest tile index
        f32x4 acc[4][4] = {};            // [tile][mi], 64 VGPRs
        for (int k0 = kmin; k0 < LF_; k0 += 32) {
            int ks = k0 >> 5;
            bf16x8 a[4];
#pragma unroll
            for (int mi = 0; mi < 4; ++mi) a[mi] = phiFrag(phiB, mi * 16 + cl, k0 + q * 8);
#pragma unroll
            for (int j = 0; j < 4; ++j) {
                if (k0 >= kstart[j]) {          // wave-uniform branch; load gated too
                    bf16x8 b = fragGL(ltf, tl[j] * 16 + ks, ln);
#pragma unroll
                    for (int mi = 0; mi < 4; ++mi)
                        acc[j][mi] = __builtin_amdgcn_mfma_f32_16x16x32_bf16(
                            a[mi], b, acc[j][mi], 0, 0, 0);
                }
            }
        }
        float vacc[4][4];
#pragma unroll
        for (int mi = 0; mi < 4; ++mi)
#pragma unroll
            for (int r = 0; r < 4; ++r) {
                float s = 0.f;
#pragma unroll
                for (int j = 0; j < 4; ++j) { float t = acc[j][mi][r]; s += t * t; }
                s += __shfl_xor(s, 1, 64);
                s += __shfl_xor(s, 2, 64);
                s += __shfl_xor(s, 4, 64);
                s += __shfl_xor(s, 8, 64);
                vacc[mi][r] = s;
            }
        if (cl == 0)
#pragma unroll
            for (int mi = 0; mi < 4; ++mi)
#pragma unroll
                for (int r = 0; r < 4; ++r)
                    vfp[wv * 64 + mi * 16 + q * 4 + r] = vacc[mi][r];
    }
    __syncthreads();
    if (tid < 64) {
        float v = vfb[tid] + qcp[0];
#pragma unroll
        for (int w = 0; w < 8; ++w) v += vfp[w * 64 + tid];
        vf[m0 + tid] = v;
    }
}

extern "C" void kernel_launch(void* const* d_in, const int* in_sizes, int n_in,
                              void* d_out, int out_size, void* d_ws, size_t ws_size,
                              hipStream_t stream) {
    const float* x  = (const float*)d_in[0];
    const float* w1 = (const float*)d_in[1];
    const float* b1 = (const float*)d_in[2];
    const float* w2 = (const float*)d_in[3];
    const float* lv = (const float*)d_in[4];
    const float* qb = (const float*)d_in[5];
    const float* qc = (const float*)d_in[6];

    char* ws = (char*)d_ws;
    __hip_bfloat16* ltf = (__hip_bfloat16*)(ws + OFF_LTF);
    __hip_bfloat16* w1f = (__hip_bfloat16*)(ws + OFF_W1F);
    __hip_bfloat16* w2f = (__hip_bfloat16*)(ws + OFF_W2F);

    float* pi = (float*)d_out;
    float* vf = pi + (size_t)B_ * OUT_;

    k_prep <<<172, 256, 0, stream>>>(w1, w2, lv, qb, w1f, w2f, ltf);
    k_fused<<<B_ / 64, 512, 0, stream>>>(x, w1f, b1, w2f, ltf, qc, pi, vf);
}

// Round 4
// 103.438 us; speedup vs baseline: 1.0454x; 1.0454x over previous
//
#include <hip/hip_runtime.h>
#include <hip/hip_bf16.h>
#include <stdint.h>

typedef short bf16x8 __attribute__((ext_vector_type(8)));
typedef short bf16x4 __attribute__((ext_vector_type(4)));
typedef float f32x4 __attribute__((ext_vector_type(4)));

#define DEVI static __device__ __forceinline__

constexpr int B_   = 32768;
constexpr int IN_  = 128;
constexpr int LF_  = 512;
constexpr int OUT_ = 32;

// ---- workspace layout (bytes) ----
// All B-side matrices stored in MFMA-fragment order:
//   chunk(tile,kstep) at base + chunk*64*16B; lane ln reads +ln*16B (coalesced).
// Fragment content for lane ln: row n = tile*16 + (ln&15), k = kstep*32 + (ln>>4)*8 .. +7.
constexpr size_t OFF_LTF = 0;                    // 32 tiles x 16 ks x 1KB = 524,288
constexpr size_t OFF_W1F = 524288;               // 32 tiles x 4 ks x 1KB  = 131,072
constexpr size_t OFF_W2F = OFF_W1F + 131072;     // 3 tiles x 16 ks x 1KB  = 49,152

DEVI short f2bs(float f) { __hip_bfloat16 h = __float2bfloat16(f); return *(short*)&h; }

// fast tanh: 1 - 2/(e^{2v}+1)
DEVI float tanh_fast(float v) {
    float e = __expf(2.0f * v);
    return 1.0f - 2.0f * __builtin_amdgcn_rcpf(e + 1.0f);
}

// coalesced fragment load: chunk = tile*ksteps + ks
DEVI bf16x8 fragGL(const __hip_bfloat16* base, int chunk, int ln) {
    return *(const bf16x8*)(base + ((size_t)chunk * 64 + ln) * 8);
}

// phi LDS tile: 64 rows x 64 chunks(16B); slot = row*64 + ((k>>3) ^ (row&7))
DEVI bf16x8 phiFrag(const char* p, int row, int kofs) {
    int c = (kofs >> 3) ^ (row & 7);
    return *(const bf16x8*)(p + (size_t)((row << 6) + c) * 16);
}
// x LDS tile: 64 rows x 16 chunks; slot = row*16 + ((k>>3) ^ (row&15))
DEVI bf16x8 xFrag(const char* p, int row, int kofs) {
    int c = (kofs >> 3) ^ (row & 15);
    return *(const bf16x8*)(p + (size_t)((row << 4) + c) * 16);
}

// ---------------- prep: build fragment-order W1F / W2F / LTF ----------------
// one thread per 16B chunk: 8192 (w1f) + 3072 (w2f) + 32768 (ltf) = 44032
__global__ __launch_bounds__(256) void k_prep(
        const float* __restrict__ w1, const float* __restrict__ w2,
        const float* __restrict__ lv, const float* __restrict__ qb,
        __hip_bfloat16* __restrict__ w1f, __hip_bfloat16* __restrict__ w2f,
        __hip_bfloat16* __restrict__ ltf) {
    int cid = blockIdx.x * 256 + threadIdx.x;
    if (cid < 8192) {                       // W1F: nt(32) x ks(4) x ln(64)
        int ln = cid & 63, ks = (cid >> 6) & 3, nt = cid >> 8;
        int n = nt * 16 + (ln & 15), kb = ks * 32 + (ln >> 4) * 8;
        const float* src = w1 + (size_t)n * IN_ + kb;
        bf16x8 o;
#pragma unroll
        for (int i = 0; i < 8; ++i) o[i] = f2bs(src[i]);
        *(bf16x8*)(w1f + (size_t)cid * 8) = o;
    } else if (cid < 11264) {               // W2F: nt(3) x ks(16) x ln(64)
        int c2 = cid - 8192;
        int ln = c2 & 63, ks = (c2 >> 6) & 15, nt = c2 >> 10;
        int n = nt * 16 + (ln & 15), kb = ks * 32 + (ln >> 4) * 8;
        bf16x8 o;
#pragma unroll
        for (int i = 0; i < 8; ++i) {
            float v = (n < OUT_) ? w2[(size_t)n * LF_ + kb + i]
                                 : (n == OUT_ ? qb[kb + i] : 0.f);
            o[i] = f2bs(v);
        }
        *(bf16x8*)(w2f + (size_t)c2 * 8) = o;
    } else if (cid < 44032) {               // LTF: t(32) x ks(16) x ln(64)
        int c3 = cid - 11264;
        int ln = c3 & 63, ks = (c3 >> 6) & 15, t = c3 >> 10;
        int j = t * 16 + (ln & 15), kb = ks * 32 + (ln >> 4) * 8;
        bf16x8 o;
#pragma unroll
        for (int i = 0; i < 8; ++i) {
            int k = kb + i;                 // Lt[j][k] = L[k][j], zero for k<j
            o[i] = (k >= j) ? f2bs(lv[(size_t)k * (k + 1) / 2 + j]) : (short)0;
        }
        *(bf16x8*)(ltf + (size_t)c3 * 8) = o;
    }
}

// ---------------- fused: x->phi(LDS)->pi,vf ----------------
// M=64 rows/block, 512 blocks (all resident: 2 blocks/CU).
// LDS: phi 64KB | stage 16KB (x, then vfb/vfp alias) = 80KB.
// Phase 1 uses SWAPPED operands (A=W1, B=x) so each lane's 4 acc values are
// 4 consecutive phi columns -> packed ds_write_b64 epilogue (4x fewer LDS ops).
// Phase 3 uses GATED one-step prefetch of ltf fragments (latency hidden, no
// extra L2 traffic: loads issue only once k+32 >= kstart[tile]).
__global__ __launch_bounds__(512, 4) void k_fused(
        const float* __restrict__ x, const __hip_bfloat16* __restrict__ w1f,
        const float* __restrict__ b1, const __hip_bfloat16* __restrict__ w2f,
        const __hip_bfloat16* __restrict__ ltf, const float* __restrict__ qcp,
        float* __restrict__ pi, float* __restrict__ vf) {
    __shared__ char smem[81920];
    char*  phiB  = smem;
    char*  stage = smem + 65536;
    float* vfb   = (float*)stage;          // 64 f32 (alias; valid after phase-1 barrier)
    float* vfp   = (float*)(stage + 256);  // 8x64 f32

    const int tid = threadIdx.x, wv = tid >> 6, ln = tid & 63;
    const int cl = ln & 15, q = ln >> 4;
    const int m0 = blockIdx.x * 64;

    // ---- phase 0: load+cast x tile (64x128 fp32 -> bf16) into LDS ----
#pragma unroll
    for (int it = 0; it < 2; ++it) {
        int slot = it * 512 + tid, row = slot >> 4, cg = slot & 15;
        const float4* p = (const float4*)(x + (size_t)(m0 + row) * IN_ + cg * 8);
        float4 u0 = p[0], u1 = p[1];
        bf16x8 pk;
        pk[0] = f2bs(u0.x); pk[1] = f2bs(u0.y); pk[2] = f2bs(u0.z); pk[3] = f2bs(u0.w);
        pk[4] = f2bs(u1.x); pk[5] = f2bs(u1.y); pk[6] = f2bs(u1.z); pk[7] = f2bs(u1.w);
        *(bf16x8*)(stage + (size_t)((row << 4) + (cg ^ (row & 15))) * 16) = pk;
    }
    __syncthreads();

    // ---- phase 1: phi = tanh(x @ W1^T + b1), swapped operands ----
    // D row-space = W1 rows (n = q*4+r), col-space = x rows (m = cl).
    {
        f32x4 acc[4][4] = {};   // [ni][mi], 64 VGPRs
        bf16x8 an[4];
#pragma unroll
        for (int ni = 0; ni < 4; ++ni) an[ni] = fragGL(w1f, (4 * wv + ni) * 4, ln);
#pragma unroll
        for (int ks = 0; ks < 4; ++ks) {
            bf16x8 bx[4];
#pragma unroll
            for (int mi = 0; mi < 4; ++mi)
                bx[mi] = xFrag(stage, mi * 16 + cl, ks * 32 + q * 8);
            bf16x8 ac[4];
#pragma unroll
            for (int ni = 0; ni < 4; ++ni) ac[ni] = an[ni];
            if (ks < 3)
#pragma unroll
                for (int ni = 0; ni < 4; ++ni)
                    an[ni] = fragGL(w1f, (4 * wv + ni) * 4 + ks + 1, ln);
#pragma unroll
            for (int ni = 0; ni < 4; ++ni)
#pragma unroll
                for (int mi = 0; mi < 4; ++mi)
                    acc[ni][mi] = __builtin_amdgcn_mfma_f32_16x16x32_bf16(
                        ac[ni], bx[mi], acc[ni][mi], 0, 0, 0);
        }
        // epilogue: bias + tanh + packed b64 stores (4 consecutive cols/lane)
#pragma unroll
        for (int ni = 0; ni < 4; ++ni) {
            float4 bv = *(const float4*)(b1 + wv * 64 + ni * 16 + q * 4);
            int colb = wv * 8 + ni * 2 + (q >> 1);     // col>>3
#pragma unroll
            for (int mi = 0; mi < 4; ++mi) {
                int row = mi * 16 + cl;
                bf16x4 pk;
                pk[0] = f2bs(tanh_fast(acc[ni][mi][0] + bv.x));
                pk[1] = f2bs(tanh_fast(acc[ni][mi][1] + bv.y));
                pk[2] = f2bs(tanh_fast(acc[ni][mi][2] + bv.z));
                pk[3] = f2bs(tanh_fast(acc[ni][mi][3] + bv.w));
                int c = colb ^ (row & 7);
                *(bf16x4*)(phiB + (size_t)row * 1024 + c * 16 + (q & 1) * 8) = pk;
            }
        }
    }
    __syncthreads();   // phi complete; x/stage dead -> vfb/vfp alias valid

    // ---- phase 2: pi = phi @ W2ext^T; 12 (m,n) wave-tiles over 8 waves ----
    // waves 0-3 run two INTERLEAVED independent chains (halved dep latency).
    if (wv < 4) {
        int mi0 = (2 * wv) & 3, ni0 = (2 * wv) >> 2;
        int mi1 = (2 * wv + 1) & 3, ni1 = (2 * wv + 1) >> 2;
        f32x4 a20 = {}, a21 = {};
#pragma unroll 4
        for (int ks = 0; ks < 16; ++ks) {
            bf16x8 p0 = phiFrag(phiB, mi0 * 16 + cl, ks * 32 + q * 8);
            bf16x8 b0 = fragGL(w2f, ni0 * 16 + ks, ln);
            a20 = __builtin_amdgcn_mfma_f32_16x16x32_bf16(p0, b0, a20, 0, 0, 0);
            bf16x8 p1 = phiFrag(phiB, mi1 * 16 + cl, ks * 32 + q * 8);
            bf16x8 b1f = fragGL(w2f, ni1 * 16 + ks, ln);
            a21 = __builtin_amdgcn_mfma_f32_16x16x32_bf16(p1, b1f, a21, 0, 0, 0);
        }
#pragma unroll
        for (int r = 0; r < 4; ++r) {
            int row0 = mi0 * 16 + q * 4 + r, col0 = ni0 * 16 + cl;
            if (col0 < OUT_) pi[(size_t)(m0 + row0) * OUT_ + col0] = a20[r];
            int row1 = mi1 * 16 + q * 4 + r, col1 = ni1 * 16 + cl;
            if (col1 < OUT_) pi[(size_t)(m0 + row1) * OUT_ + col1] = a21[r];
        }
    } else {
        int mi = wv - 4, ni = 2;                    // tiles 8..11
        f32x4 a2a = {}, a2b = {};
#pragma unroll
        for (int ks = 0; ks < 16; ks += 2) {        // two chains over even/odd ks
            bf16x8 pe = phiFrag(phiB, mi * 16 + cl, ks * 32 + q * 8);
            bf16x8 be = fragGL(w2f, ni * 16 + ks, ln);
            a2a = __builtin_amdgcn_mfma_f32_16x16x32_bf16(pe, be, a2a, 0, 0, 0);
            bf16x8 po = phiFrag(phiB, mi * 16 + cl, (ks + 1) * 32 + q * 8);
            bf16x8 bo = fragGL(w2f, ni * 16 + ks + 1, ln);
            a2b = __builtin_amdgcn_mfma_f32_16x16x32_bf16(po, bo, a2b, 0, 0, 0);
        }
        f32x4 a2 = a2a + a2b;
#pragma unroll
        for (int r = 0; r < 4; ++r) {
            int row = mi * 16 + q * 4 + r, col = ni * 16 + cl;
            if (col < OUT_)       pi[(size_t)(m0 + row) * OUT_ + col] = a2[r];
            else if (col == OUT_) vfb[row] = a2[r];   // phi.qb
        }
    }

    // ---- phase 3: y = rowsum((phi @ L)^2); mirrored tiles, gated prefetch ----
    {
        int tl[4] = { wv, 15 - wv, 16 + wv, 31 - wv };
        int kstart[4];
#pragma unroll
        for (int j = 0; j < 4; ++j) kstart[j] = (tl[j] * 16) & ~31;  // exact: Lt zero-padded
        int kmin = kstart[0];            // tl[0] is the smallest tile index
        f32x4 acc[4][4] = {};            // [tile][mi], 64 VGPRs
        bf16x8 bcur[4] = {};
#pragma unroll
        for (int j = 0; j < 4; ++j)
            if (kmin >= kstart[j]) bcur[j] = fragGL(ltf, tl[j] * 16 + (kmin >> 5), ln);
        for (int k0 = kmin; k0 < LF_; k0 += 32) {
            bf16x8 a[4];
#pragma unroll
            for (int mi = 0; mi < 4; ++mi) a[mi] = phiFrag(phiB, mi * 16 + cl, k0 + q * 8);
            int k1 = k0 + 32;
            bf16x8 bnx[4];
#pragma unroll
            for (int j = 0; j < 4; ++j)      // gated prefetch: same traffic, hidden latency
                if (k1 < LF_ && k1 >= kstart[j])
                    bnx[j] = fragGL(ltf, tl[j] * 16 + (k1 >> 5), ln);
#pragma unroll
            for (int j = 0; j < 4; ++j) {
                if (k0 >= kstart[j]) {       // wave-uniform branch
#pragma unroll
                    for (int mi = 0; mi < 4; ++mi)
                        acc[j][mi] = __builtin_amdgcn_mfma_f32_16x16x32_bf16(
                            a[mi], bcur[j], acc[j][mi], 0, 0, 0);
                }
            }
#pragma unroll
            for (int j = 0; j < 4; ++j)
                if (k1 < LF_ && k1 >= kstart[j]) bcur[j] = bnx[j];
        }
        float vacc[4][4];
#pragma unroll
        for (int mi = 0; mi < 4; ++mi)
#pragma unroll
            for (int r = 0; r < 4; ++r) {
                float s = 0.f;
#pragma unroll
                for (int j = 0; j < 4; ++j) { float t = acc[j][mi][r]; s += t * t; }
                s += __shfl_xor(s, 1, 64);
                s += __shfl_xor(s, 2, 64);
                s += __shfl_xor(s, 4, 64);
                s += __shfl_xor(s, 8, 64);
                vacc[mi][r] = s;
            }
        if (cl == 0)
#pragma unroll
            for (int mi = 0; mi < 4; ++mi)
#pragma unroll
                for (int r = 0; r < 4; ++r)
                    vfp[wv * 64 + mi * 16 + q * 4 + r] = vacc[mi][r];
    }
    __syncthreads();
    if (tid < 64) {
        float v = vfb[tid] + qcp[0];
#pragma unroll
        for (int w = 0; w < 8; ++w) v += vfp[w * 64 + tid];
        vf[m0 + tid] = v;
    }
}

extern "C" void kernel_launch(void* const* d_in, const int* in_sizes, int n_in,
                              void* d_out, int out_size, void* d_ws, size_t ws_size,
                              hipStream_t stream) {
    const float* x  = (const float*)d_in[0];
    const float* w1 = (const float*)d_in[1];
    const float* b1 = (const float*)d_in[2];
    const float* w2 = (const float*)d_in[3];
    const float* lv = (const float*)d_in[4];
    const float* qb = (const float*)d_in[5];
    const float* qc = (const float*)d_in[6];

    char* ws = (char*)d_ws;
    __hip_bfloat16* ltf = (__hip_bfloat16*)(ws + OFF_LTF);
    __hip_bfloat16* w1f = (__hip_bfloat16*)(ws + OFF_W1F);
    __hip_bfloat16* w2f = (__hip_bfloat16*)(ws + OFF_W2F);

    float* pi = (float*)d_out;
    float* vf = pi + (size_t)B_ * OUT_;

    k_prep <<<172, 256, 0, stream>>>(w1, w2, lv, qb, w1f, w2f, ltf);
    k_fused<<<B_ / 64, 512, 0, stream>>>(x, w1f, b1, w2f, ltf, qc, pi, vf);
}

// Round 10
// 103.128 us; speedup vs baseline: 1.0485x; 1.0030x over previous
//
#include <hip/hip_runtime.h>
#include <hip/hip_bf16.h>
#include <stdint.h>

typedef short bf16x8 __attribute__((ext_vector_type(8)));
typedef short bf16x4 __attribute__((ext_vector_type(4)));
typedef float f32x4 __attribute__((ext_vector_type(4)));

#define DEVI static __device__ __forceinline__

constexpr int B_   = 32768;
constexpr int IN_  = 128;
constexpr int LF_  = 512;
constexpr int OUT_ = 32;

// ---- workspace layout (bytes) ----
// All B-side matrices stored in MFMA-fragment order:
//   chunk(tile,kstep) at base + chunk*64*16B; lane ln reads +ln*16B (coalesced).
// Fragment content for lane ln: row n = tile*16 + (ln&15), k = kstep*32 + (ln>>4)*8 .. +7.
constexpr size_t OFF_LTF = 0;                    // 32 tiles x 16 ks x 1KB = 524,288
constexpr size_t OFF_W1F = 524288;               // 32 tiles x 4 ks x 1KB  = 131,072
constexpr size_t OFF_W2F = OFF_W1F + 131072;     // 3 tiles x 16 ks x 1KB  = 49,152

DEVI short f2bs(float f) { __hip_bfloat16 h = __float2bfloat16(f); return *(short*)&h; }

// fast tanh: 1 - 2/(e^{2v}+1)
DEVI float tanh_fast(float v) {
    float e = __expf(2.0f * v);
    return 1.0f - 2.0f * __builtin_amdgcn_rcpf(e + 1.0f);
}

// coalesced fragment load: chunk = tile*ksteps + ks
DEVI bf16x8 fragGL(const __hip_bfloat16* base, int chunk, int ln) {
    return *(const bf16x8*)(base + ((size_t)chunk * 64 + ln) * 8);
}

// phi LDS tile: 64 rows x 64 chunks(16B); slot = row*64 + ((k>>3) ^ (row&7))
DEVI bf16x8 phiFrag(const char* p, int row, int kofs) {
    int c = (kofs >> 3) ^ (row & 7);
    return *(const bf16x8*)(p + (size_t)((row << 6) + c) * 16);
}
// x LDS tile: 64 rows x 16 chunks; slot = row*16 + ((k>>3) ^ (row&15))
DEVI bf16x8 xFrag(const char* p, int row, int kofs) {
    int c = (kofs >> 3) ^ (row & 15);
    return *(const bf16x8*)(p + (size_t)((row << 4) + c) * 16);
}

// ---------------- prep: build fragment-order W1F / W2F / LTF ----------------
// one thread per 16B chunk: 8192 (w1f) + 3072 (w2f) + 32768 (ltf) = 44032
__global__ __launch_bounds__(256) void k_prep(
        const float* __restrict__ w1, const float* __restrict__ w2,
        const float* __restrict__ lv, const float* __restrict__ qb,
        __hip_bfloat16* __restrict__ w1f, __hip_bfloat16* __restrict__ w2f,
        __hip_bfloat16* __restrict__ ltf) {
    int cid = blockIdx.x * 256 + threadIdx.x;
    if (cid < 8192) {                       // W1F: nt(32) x ks(4) x ln(64)
        int ln = cid & 63, ks = (cid >> 6) & 3, nt = cid >> 8;
        int n = nt * 16 + (ln & 15), kb = ks * 32 + (ln >> 4) * 8;
        const float* src = w1 + (size_t)n * IN_ + kb;
        bf16x8 o;
#pragma unroll
        for (int i = 0; i < 8; ++i) o[i] = f2bs(src[i]);
        *(bf16x8*)(w1f + (size_t)cid * 8) = o;
    } else if (cid < 11264) {               // W2F: nt(3) x ks(16) x ln(64)
        int c2 = cid - 8192;
        int ln = c2 & 63, ks = (c2 >> 6) & 15, nt = c2 >> 10;
        int n = nt * 16 + (ln & 15), kb = ks * 32 + (ln >> 4) * 8;
        bf16x8 o;
#pragma unroll
        for (int i = 0; i < 8; ++i) {
            float v = (n < OUT_) ? w2[(size_t)n * LF_ + kb + i]
                                 : (n == OUT_ ? qb[kb + i] : 0.f);
            o[i] = f2bs(v);
        }
        *(bf16x8*)(w2f + (size_t)c2 * 8) = o;
    } else if (cid < 44032) {               // LTF: t(32) x ks(16) x ln(64)
        int c3 = cid - 11264;
        int ln = c3 & 63, ks = (c3 >> 6) & 15, t = c3 >> 10;
        int j = t * 16 + (ln & 15), kb = ks * 32 + (ln >> 4) * 8;
        bf16x8 o;
#pragma unroll
        for (int i = 0; i < 8; ++i) {
            int k = kb + i;                 // Lt[j][k] = L[k][j], zero for k<j
            o[i] = (k >= j) ? f2bs(lv[(size_t)k * (k + 1) / 2 + j]) : (short)0;
        }
        *(bf16x8*)(ltf + (size_t)c3 * 8) = o;
    }
}

// ---------------- fused: x->phi(LDS)->pi,vf ----------------
// M=64 rows/block, 512 blocks (all resident: 2 blocks/CU).
// LDS: phi 64KB | stage 16KB (x, then vfb/vfp alias) = 80KB.
// Latency-hiding discipline: every phase's FIRST global fragment load is
// hoisted above the preceding barrier/VALU burst so L2 latency overlaps:
//   - W1 frags issued before phase-0 x staging
//   - W2 first frag issued before phase-1 tanh epilogue (+ per-ks rotation)
//   - ltf first frag + geometry issued before the phase-1->2 barrier
// Waves 0-3 share one W2 fragment per ks for both their tiles (dedupe).
__global__ __launch_bounds__(512, 4) void k_fused(
        const float* __restrict__ x, const __hip_bfloat16* __restrict__ w1f,
        const float* __restrict__ b1, const __hip_bfloat16* __restrict__ w2f,
        const __hip_bfloat16* __restrict__ ltf, const float* __restrict__ qcp,
        float* __restrict__ pi, float* __restrict__ vf) {
    __shared__ char smem[81920];
    char*  phiB  = smem;
    char*  stage = smem + 65536;
    float* vfb   = (float*)stage;          // 64 f32 (alias; valid after phase-1 barrier)
    float* vfp   = (float*)(stage + 256);  // 8x64 f32

    const int tid = threadIdx.x, wv = tid >> 6, ln = tid & 63;
    const int cl = ln & 15, q = ln >> 4;
    const int m0 = blockIdx.x * 64;

    // ---- early: phase-1 first W1 fragments (LDS-independent; hide under phase 0) ----
    bf16x8 an[4];
#pragma unroll
    for (int ni = 0; ni < 4; ++ni) an[ni] = fragGL(w1f, (4 * wv + ni) * 4, ln);

    // ---- phase 0: load+cast x tile (64x128 fp32 -> bf16) into LDS ----
#pragma unroll
    for (int it = 0; it < 2; ++it) {
        int slot = it * 512 + tid, row = slot >> 4, cg = slot & 15;
        const float4* p = (const float4*)(x + (size_t)(m0 + row) * IN_ + cg * 8);
        float4 u0 = p[0], u1 = p[1];
        bf16x8 pk;
        pk[0] = f2bs(u0.x); pk[1] = f2bs(u0.y); pk[2] = f2bs(u0.z); pk[3] = f2bs(u0.w);
        pk[4] = f2bs(u1.x); pk[5] = f2bs(u1.y); pk[6] = f2bs(u1.z); pk[7] = f2bs(u1.w);
        *(bf16x8*)(stage + (size_t)((row << 4) + (cg ^ (row & 15))) * 16) = pk;
    }
    __syncthreads();

    // phase-2 tile geometry (used for prefetch hoisting below)
    const int p2ni = (wv < 4) ? (wv >> 1) : 2;

    // ---- phase 1: phi = tanh(x @ W1^T + b1), swapped operands ----
    // D row-space = W1 rows (n = q*4+r), col-space = x rows (m = cl).
    {
        f32x4 acc[4][4] = {};   // [ni][mi], 64 VGPRs
#pragma unroll
        for (int ks = 0; ks < 4; ++ks) {
            bf16x8 bx[4];
#pragma unroll
            for (int mi = 0; mi < 4; ++mi)
                bx[mi] = xFrag(stage, mi * 16 + cl, ks * 32 + q * 8);
            bf16x8 ac[4];
#pragma unroll
            for (int ni = 0; ni < 4; ++ni) ac[ni] = an[ni];
            if (ks < 3)
#pragma unroll
                for (int ni = 0; ni < 4; ++ni)
                    an[ni] = fragGL(w1f, (4 * wv + ni) * 4 + ks + 1, ln);
#pragma unroll
            for (int ni = 0; ni < 4; ++ni)
#pragma unroll
                for (int mi = 0; mi < 4; ++mi)
                    acc[ni][mi] = __builtin_amdgcn_mfma_f32_16x16x32_bf16(
                        ac[ni], bx[mi], acc[ni][mi], 0, 0, 0);
        }
        // hoisted phase-2 first B fragment (hides under tanh epilogue + barrier)
        bf16x8 b2cur = fragGL(w2f, p2ni * 16, ln);

        // epilogue: bias + tanh + packed b64 stores (4 consecutive cols/lane)
#pragma unroll
        for (int ni = 0; ni < 4; ++ni) {
            float4 bv = *(const float4*)(b1 + wv * 64 + ni * 16 + q * 4);
            int colb = wv * 8 + ni * 2 + (q >> 1);     // col>>3
#pragma unroll
            for (int mi = 0; mi < 4; ++mi) {
                int row = mi * 16 + cl;
                bf16x4 pk;
                pk[0] = f2bs(tanh_fast(acc[ni][mi][0] + bv.x));
                pk[1] = f2bs(tanh_fast(acc[ni][mi][1] + bv.y));
                pk[2] = f2bs(tanh_fast(acc[ni][mi][2] + bv.z));
                pk[3] = f2bs(tanh_fast(acc[ni][mi][3] + bv.w));
                int c = colb ^ (row & 7);
                *(bf16x4*)(phiB + (size_t)row * 1024 + c * 16 + (q & 1) * 8) = pk;
            }
        }

        // ---- hoisted phase-3 geometry + first ltf fragment (hides under phase 2) ----
        int tl[4] = { wv, 15 - wv, 16 + wv, 31 - wv };
        int kstart[4];
#pragma unroll
        for (int j = 0; j < 4; ++j) kstart[j] = (tl[j] * 16) & ~31;  // exact: Lt zero-padded
        int kmin = kstart[0];            // tl[0] is the smallest tile index
        bf16x8 bcur[4] = {};
        bcur[0] = fragGL(ltf, tl[0] * 16 + (kmin >> 5), ln);   // only j=0 active at kmin

        __syncthreads();   // phi complete; x/stage dead -> vfb/vfp alias valid

        // ---- phase 2: pi = phi @ W2ext^T; 12 (m,n) wave-tiles over 8 waves ----
        if (wv < 4) {
            // two row-tiles, SHARED column tile (ni = wv>>1): one B per ks
            int mi0 = (2 * wv) & 3, mi1 = mi0 + 1;
            f32x4 a20 = {}, a21 = {};
#pragma unroll
            for (int ks = 0; ks < 16; ++ks) {
                bf16x8 bnx = (ks < 15) ? fragGL(w2f, p2ni * 16 + ks + 1, ln) : b2cur;
                bf16x8 p0 = phiFrag(phiB, mi0 * 16 + cl, ks * 32 + q * 8);
                a20 = __builtin_amdgcn_mfma_f32_16x16x32_bf16(p0, b2cur, a20, 0, 0, 0);
                bf16x8 p1 = phiFrag(phiB, mi1 * 16 + cl, ks * 32 + q * 8);
                a21 = __builtin_amdgcn_mfma_f32_16x16x32_bf16(p1, b2cur, a21, 0, 0, 0);
                b2cur = bnx;
            }
#pragma unroll
            for (int r = 0; r < 4; ++r) {
                int col = p2ni * 16 + cl;                      // always < 32
                pi[(size_t)(m0 + mi0 * 16 + q * 4 + r) * OUT_ + col] = a20[r];
                pi[(size_t)(m0 + mi1 * 16 + q * 4 + r) * OUT_ + col] = a21[r];
            }
        } else {
            // one row-tile, qb column tile (ni=2); parity dual-chain
            int mi = wv - 4;
            f32x4 a2c0 = {}, a2c1 = {};
#pragma unroll
            for (int ks = 0; ks < 16; ++ks) {
                bf16x8 bnx = (ks < 15) ? fragGL(w2f, 32 + ks + 1, ln) : b2cur;
                bf16x8 p = phiFrag(phiB, mi * 16 + cl, ks * 32 + q * 8);
                if (ks & 1)
                    a2c1 = __builtin_amdgcn_mfma_f32_16x16x32_bf16(p, b2cur, a2c1, 0, 0, 0);
                else
                    a2c0 = __builtin_amdgcn_mfma_f32_16x16x32_bf16(p, b2cur, a2c0, 0, 0, 0);
                b2cur = bnx;
            }
            f32x4 a2 = a2c0 + a2c1;
            if (cl == 0)                                       // col == 32 == OUT_
#pragma unroll
                for (int r = 0; r < 4; ++r)
                    vfb[mi * 16 + q * 4 + r] = a2[r];          // phi.qb
        }

        // ---- phase 3: y = rowsum((phi @ L)^2); mirrored tiles, gated prefetch ----
        {
            f32x4 acc3[4][4] = {};           // [tile][mi], 64 VGPRs
            for (int k0 = kmin; k0 < LF_; k0 += 32) {
                bf16x8 a[4];
#pragma unroll
                for (int mi = 0; mi < 4; ++mi) a[mi] = phiFrag(phiB, mi * 16 + cl, k0 + q * 8);
                int k1 = k0 + 32;
                bf16x8 bnx[4];
#pragma unroll
                for (int j = 0; j < 4; ++j)      // gated prefetch: same traffic, hidden latency
                    if (k1 < LF_ && k1 >= kstart[j])
                        bnx[j] = fragGL(ltf, tl[j] * 16 + (k1 >> 5), ln);
#pragma unroll
                for (int j = 0; j < 4; ++j) {
                    if (k0 >= kstart[j]) {       // wave-uniform branch
#pragma unroll
                        for (int mi = 0; mi < 4; ++mi)
                            acc3[j][mi] = __builtin_amdgcn_mfma_f32_16x16x32_bf16(
                                a[mi], bcur[j], acc3[j][mi], 0, 0, 0);
                    }
                }
#pragma unroll
                for (int j = 0; j < 4; ++j)
                    if (k1 < LF_ && k1 >= kstart[j]) bcur[j] = bnx[j];
            }
            float vacc[4][4];
#pragma unroll
            for (int mi = 0; mi < 4; ++mi)
#pragma unroll
                for (int r = 0; r < 4; ++r) {
                    float s = 0.f;
#pragma unroll
                    for (int j = 0; j < 4; ++j) { float t = acc3[j][mi][r]; s += t * t; }
                    s += __shfl_xor(s, 1, 64);
                    s += __shfl_xor(s, 2, 64);
                    s += __shfl_xor(s, 4, 64);
                    s += __shfl_xor(s, 8, 64);
                    vacc[mi][r] = s;
                }
            if (cl == 0)
#pragma unroll
                for (int mi = 0; mi < 4; ++mi)
#pragma unroll
                    for (int r = 0; r < 4; ++r)
                        vfp[wv * 64 + mi * 16 + q * 4 + r] = vacc[mi][r];
        }
    }
    __syncthreads();
    if (tid < 64) {
        float v = vfb[tid] + qcp[0];
#pragma unroll
        for (int w = 0; w < 8; ++w) v += vfp[w * 64 + tid];
        vf[m0 + tid] = v;
    }
}

extern "C" void kernel_launch(void* const* d_in, const int* in_sizes, int n_in,
                              void* d_out, int out_size, void* d_ws, size_t ws_size,
                              hipStream_t stream) {
    const float* x  = (const float*)d_in[0];
    const float* w1 = (const float*)d_in[1];
    const float* b1 = (const float*)d_in[2];
    const float* w2 = (const float*)d_in[3];
    const float* lv = (const float*)d_in[4];
    const float* qb = (const float*)d_in[5];
    const float* qc = (const float*)d_in[6];

    char* ws = (char*)d_ws;
    __hip_bfloat16* ltf = (__hip_bfloat16*)(ws + OFF_LTF);
    __hip_bfloat16* w1f = (__hip_bfloat16*)(ws + OFF_W1F);
    __hip_bfloat16* w2f = (__hip_bfloat16*)(ws + OFF_W2F);

    float* pi = (float*)d_out;
    float* vf = pi + (size_t)B_ * OUT_;

    k_prep <<<172, 256, 0, stream>>>(w1, w2, lv, qb, w1f, w2f, ltf);
    k_fused<<<B_ / 64, 512, 0, stream>>>(x, w1f, b1, w2f, ltf, qc, pi, vf);
}